// Round 10
// baseline (159.553 us; speedup 1.0000x reference)
//
#include <hip/hip_runtime.h>
#include <stdint.h>

#define S_TOK 8192
#define D_DIM 768
#define B_SZ  4
#define K_TOP 512

// ---------------- Kernel A: importance[s] = 0.25 * sum_b ||h[b,s,:]|| ----------------
// One wave per token; 12 independent float4 loads; butterfly tails. (Verified absmax 0.)
__global__ __launch_bounds__(256) void importance_kernel(const float4* __restrict__ h4,
                                                         uint32_t* __restrict__ imp_u) {
    const int D4 = D_DIM / 4;               // 192
    const size_t SB = (size_t)S_TOK * D4;   // batch stride in float4
    const int wave = (blockIdx.x * blockDim.x + threadIdx.x) >> 6;  // token, < 8192
    const int lane = threadIdx.x & 63;
    const float4* r = h4 + (size_t)wave * D4 + lane;

    float4 v0 = r[0 * SB + 0],  v1 = r[0 * SB + 64],  v2 = r[0 * SB + 128];
    float4 v3 = r[1 * SB + 0],  v4 = r[1 * SB + 64],  v5 = r[1 * SB + 128];
    float4 v6 = r[2 * SB + 0],  v7 = r[2 * SB + 64],  v8 = r[2 * SB + 128];
    float4 v9 = r[3 * SB + 0],  vA = r[3 * SB + 64],  vB = r[3 * SB + 128];

    float d0 = v0.x * v0.x + v0.y * v0.y + v0.z * v0.z + v0.w * v0.w;
    float d1 = v1.x * v1.x + v1.y * v1.y + v1.z * v1.z + v1.w * v1.w;
    float d2 = v2.x * v2.x + v2.y * v2.y + v2.z * v2.z + v2.w * v2.w;
    float d3 = v3.x * v3.x + v3.y * v3.y + v3.z * v3.z + v3.w * v3.w;
    float d4 = v4.x * v4.x + v4.y * v4.y + v4.z * v4.z + v4.w * v4.w;
    float d5 = v5.x * v5.x + v5.y * v5.y + v5.z * v5.z + v5.w * v5.w;
    float d6 = v6.x * v6.x + v6.y * v6.y + v6.z * v6.z + v6.w * v6.w;
    float d7 = v7.x * v7.x + v7.y * v7.y + v7.z * v7.z + v7.w * v7.w;
    float d8 = v8.x * v8.x + v8.y * v8.y + v8.z * v8.z + v8.w * v8.w;
    float d9 = v9.x * v9.x + v9.y * v9.y + v9.z * v9.z + v9.w * v9.w;
    float dA = vA.x * vA.x + vA.y * vA.y + vA.z * vA.z + vA.w * vA.w;
    float dB = vB.x * vB.x + vB.y * vB.y + vB.z * vB.z + vB.w * vB.w;

    float a0 = d0 + d1 + d2;
    float a1 = d3 + d4 + d5;
    float a2 = d6 + d7 + d8;
    float a3 = d9 + dA + dB;
#pragma unroll
    for (int off = 32; off >= 1; off >>= 1) {
        a0 += __shfl_xor(a0, off);
        a1 += __shfl_xor(a1, off);
        a2 += __shfl_xor(a2, off);
        a3 += __shfl_xor(a3, off);
    }
    if (lane == 0) {
        float acc = sqrtf(a0) + sqrtf(a1) + sqrtf(a2) + sqrtf(a3);
        // norms are >= 0, so float bits compare as uint32 — store bits directly
        imp_u[wave] = __float_as_uint(acc * 0.25f);
    }
}

// ---------------- Kernel B: rank + pick + gather, fused (verified absmax 0) ---------
__global__ __launch_bounds__(256) void rank_gather_kernel(const uint32_t* __restrict__ imp_u,
                                                          const float4* __restrict__ h4,
                                                          float4* __restrict__ out4) {
    const int tid = threadIdx.x;
    const int tt = tid & 15;   // token within block
    const int sl = tid >> 4;   // key slice 0..15
    const int s = blockIdx.x * 16 + tt;  // global token
    __shared__ uint32_t s_part[16][17];
    __shared__ int s_wtok[16];
    __shared__ int s_wrank[16];
    __shared__ int s_nw;

    const uint32_t ks = imp_u[s];
    const uint4* sp = (const uint4*)(imp_u + sl * 512);
    uint32_t cnt = 0;
#pragma unroll 8
    for (int j4 = 0; j4 < 128; ++j4) {
        uint4 kv = sp[j4];
        const int jb = sl * 512 + j4 * 4;
        cnt += (kv.x > ks || (kv.x == ks && (jb + 0) < s)) ? 1u : 0u;
        cnt += (kv.y > ks || (kv.y == ks && (jb + 1) < s)) ? 1u : 0u;
        cnt += (kv.z > ks || (kv.z == ks && (jb + 2) < s)) ? 1u : 0u;
        cnt += (kv.w > ks || (kv.w == ks && (jb + 3) < s)) ? 1u : 0u;
    }
    s_part[sl][tt] = cnt;
    if (tid == 0) s_nw = 0;
    __syncthreads();

    if (tid < 16) {
        uint32_t r = 0;
#pragma unroll
        for (int k = 0; k < 16; ++k) r += s_part[k][tid];
        if (r < K_TOP) {
            int w = atomicAdd(&s_nw, 1);
            s_wtok[w] = blockIdx.x * 16 + tid;
            s_wrank[w] = (int)r;
        }
    }
    __syncthreads();

    const int nw = s_nw;
    const int D4 = D_DIM / 4;  // 192
    const size_t SB = (size_t)S_TOK * D4;
    for (int w = 0; w < nw; ++w) {
        const int idx = s_wtok[w];
        const int rk = s_wrank[w];
        if (tid < D4) {
            const float4* base = h4 + (size_t)idx * D4;
            float4 a = base[tid];
            float4 b = base[tid + SB];
            float4 c = base[tid + 2 * SB];
            float4 e = base[tid + 3 * SB];
            float4 r4;
            r4.x = 0.25f * (a.x + b.x + c.x + e.x);
            r4.y = 0.25f * (a.y + b.y + c.y + e.y);
            r4.z = 0.25f * (a.z + b.z + c.z + e.z);
            r4.w = 0.25f * (a.w + b.w + c.w + e.w);
            out4[(size_t)rk * D4 + tid] = r4;
        }
    }
}

// ---------------- DIAGNOSTIC probe: canonical pure-read BW over poisoned ws ---------
// 2048 blocks x 256 thr grid-stride float4 over 352 MB of ws, TWO passes (~704 MB
// FETCH). Lands #1 in rocprof top-5; its hbm_gbps = achievable pure-read BW.
// Reads only the constant 0xAA region, writes only a private sink -> deterministic.
#define PROBE_OFF_F4 (16u * 1024 * 1024 / 16)       // region starts at ws + 16 MB
#define PROBE_N_F4   (352u * 1024 * 1024 / 16)      // 352 MB = 23068672 float4
__global__ __launch_bounds__(256) void readbw_probe_kernel(const float4* __restrict__ ws4,
                                                           float* __restrict__ sink) {
    const unsigned nthr = gridDim.x * blockDim.x;   // 524288
    const unsigned gtid = blockIdx.x * blockDim.x + threadIdx.x;
    float s = 0.f;
#pragma unroll 1
    for (int pass = 0; pass < 2; ++pass) {
#pragma unroll 1
        for (size_t i = gtid; i < PROBE_N_F4; i += nthr) {
            float4 v = ws4[PROBE_OFF_F4 + i];
            s += v.x + v.y + v.z + v.w;
        }
        asm volatile("" : "+v"(s));  // defeat cross-pass load CSE
    }
    sink[gtid] = s;
}

extern "C" void kernel_launch(void* const* d_in, const int* in_sizes, int n_in,
                              void* d_out, int out_size, void* d_ws, size_t ws_size,
                              hipStream_t stream) {
    const float* h = (const float*)d_in[0];
    // d_in[1] (memory) is dead: k == MEMORY_SIZE, every row is overwritten.
    float* out = (float*)d_out;
    uint32_t* imp_u = (uint32_t*)d_ws;                       // [0, 32 KB)
    float* sink = (float*)((char*)d_ws + 8u * 1024 * 1024);  // [8 MB, 10 MB)

    importance_kernel<<<S_TOK / 4, 256, 0, stream>>>((const float4*)h, imp_u);
    rank_gather_kernel<<<K_TOP, 256, 0, stream>>>(imp_u, (const float4*)h, (float4*)out);
    // diagnostic only — removed next round
    readbw_probe_kernel<<<2048, 256, 0, stream>>>((const float4*)d_ws, sink);
}

// Round 11
// 41.575 us; speedup vs baseline: 3.8378x; 3.8378x over previous
//
#include <hip/hip_runtime.h>
#include <stdint.h>

#define S_TOK 8192
#define D_DIM 768
#define B_SZ  4
#define K_TOP 512

// ---------------- Kernel A: importance[s] = 0.25 * sum_b ||h[b,s,:]|| ----------------
// One wave per token; 12 independent float4 loads; butterfly tails. Verified absmax 0.
// NOTE (R10 probe finding): device time of the full 2-kernel pipeline is ~11.5 us
// (h is cache-resident across graph replays); measured dur_us ~40 us is the harness
// per-replay launch floor, not kernel execution.
__global__ __launch_bounds__(256) void importance_kernel(const float4* __restrict__ h4,
                                                         uint32_t* __restrict__ imp_u) {
    const int D4 = D_DIM / 4;               // 192
    const size_t SB = (size_t)S_TOK * D4;   // batch stride in float4
    const int wave = (blockIdx.x * blockDim.x + threadIdx.x) >> 6;  // token, < 8192
    const int lane = threadIdx.x & 63;
    const float4* r = h4 + (size_t)wave * D4 + lane;

    float4 v0 = r[0 * SB + 0],  v1 = r[0 * SB + 64],  v2 = r[0 * SB + 128];
    float4 v3 = r[1 * SB + 0],  v4 = r[1 * SB + 64],  v5 = r[1 * SB + 128];
    float4 v6 = r[2 * SB + 0],  v7 = r[2 * SB + 64],  v8 = r[2 * SB + 128];
    float4 v9 = r[3 * SB + 0],  vA = r[3 * SB + 64],  vB = r[3 * SB + 128];

    float d0 = v0.x * v0.x + v0.y * v0.y + v0.z * v0.z + v0.w * v0.w;
    float d1 = v1.x * v1.x + v1.y * v1.y + v1.z * v1.z + v1.w * v1.w;
    float d2 = v2.x * v2.x + v2.y * v2.y + v2.z * v2.z + v2.w * v2.w;
    float d3 = v3.x * v3.x + v3.y * v3.y + v3.z * v3.z + v3.w * v3.w;
    float d4 = v4.x * v4.x + v4.y * v4.y + v4.z * v4.z + v4.w * v4.w;
    float d5 = v5.x * v5.x + v5.y * v5.y + v5.z * v5.z + v5.w * v5.w;
    float d6 = v6.x * v6.x + v6.y * v6.y + v6.z * v6.z + v6.w * v6.w;
    float d7 = v7.x * v7.x + v7.y * v7.y + v7.z * v7.z + v7.w * v7.w;
    float d8 = v8.x * v8.x + v8.y * v8.y + v8.z * v8.z + v8.w * v8.w;
    float d9 = v9.x * v9.x + v9.y * v9.y + v9.z * v9.z + v9.w * v9.w;
    float dA = vA.x * vA.x + vA.y * vA.y + vA.z * vA.z + vA.w * vA.w;
    float dB = vB.x * vB.x + vB.y * vB.y + vB.z * vB.z + vB.w * vB.w;

    float a0 = d0 + d1 + d2;
    float a1 = d3 + d4 + d5;
    float a2 = d6 + d7 + d8;
    float a3 = d9 + dA + dB;
#pragma unroll
    for (int off = 32; off >= 1; off >>= 1) {
        a0 += __shfl_xor(a0, off);
        a1 += __shfl_xor(a1, off);
        a2 += __shfl_xor(a2, off);
        a3 += __shfl_xor(a3, off);
    }
    if (lane == 0) {
        float acc = sqrtf(a0) + sqrtf(a1) + sqrtf(a2) + sqrtf(a3);
        // norms are >= 0, so float bits compare as uint32 — store bits directly
        imp_u[wave] = __float_as_uint(acc * 0.25f);
    }
}

// ---------------- Kernel B: rank + pick + gather, fused (verified absmax 0) ---------
// 512 blocks x 256 threads. Block b owns tokens [b*16, b*16+16). Thread (sl,tt)
// counts token tt's rank contribution over key slice [sl*512, +512) (imp: 32 KB,
// cache-resident). LDS 16x16 reduce -> exact rank (bijection: value desc, index asc).
// Winners (rank < 512, avg 1/block) gathered by the whole block into out[rank].
__global__ __launch_bounds__(256) void rank_gather_kernel(const uint32_t* __restrict__ imp_u,
                                                          const float4* __restrict__ h4,
                                                          float4* __restrict__ out4) {
    const int tid = threadIdx.x;
    const int tt = tid & 15;   // token within block
    const int sl = tid >> 4;   // key slice 0..15
    const int s = blockIdx.x * 16 + tt;  // global token
    __shared__ uint32_t s_part[16][17];
    __shared__ int s_wtok[16];
    __shared__ int s_wrank[16];
    __shared__ int s_nw;

    const uint32_t ks = imp_u[s];
    const uint4* sp = (const uint4*)(imp_u + sl * 512);
    uint32_t cnt = 0;
#pragma unroll 8
    for (int j4 = 0; j4 < 128; ++j4) {
        uint4 kv = sp[j4];
        const int jb = sl * 512 + j4 * 4;
        cnt += (kv.x > ks || (kv.x == ks && (jb + 0) < s)) ? 1u : 0u;
        cnt += (kv.y > ks || (kv.y == ks && (jb + 1) < s)) ? 1u : 0u;
        cnt += (kv.z > ks || (kv.z == ks && (jb + 2) < s)) ? 1u : 0u;
        cnt += (kv.w > ks || (kv.w == ks && (jb + 3) < s)) ? 1u : 0u;
    }
    s_part[sl][tt] = cnt;
    if (tid == 0) s_nw = 0;
    __syncthreads();

    if (tid < 16) {
        uint32_t r = 0;
#pragma unroll
        for (int k = 0; k < 16; ++k) r += s_part[k][tid];
        if (r < K_TOP) {
            int w = atomicAdd(&s_nw, 1);
            s_wtok[w] = blockIdx.x * 16 + tid;
            s_wrank[w] = (int)r;
        }
    }
    __syncthreads();

    const int nw = s_nw;
    const int D4 = D_DIM / 4;  // 192
    const size_t SB = (size_t)S_TOK * D4;
    for (int w = 0; w < nw; ++w) {
        const int idx = s_wtok[w];
        const int rk = s_wrank[w];
        if (tid < D4) {
            const float4* base = h4 + (size_t)idx * D4;
            float4 a = base[tid];
            float4 b = base[tid + SB];
            float4 c = base[tid + 2 * SB];
            float4 e = base[tid + 3 * SB];
            float4 r4;
            r4.x = 0.25f * (a.x + b.x + c.x + e.x);
            r4.y = 0.25f * (a.y + b.y + c.y + e.y);
            r4.z = 0.25f * (a.z + b.z + c.z + e.z);
            r4.w = 0.25f * (a.w + b.w + c.w + e.w);
            out4[(size_t)rk * D4 + tid] = r4;
        }
    }
}

extern "C" void kernel_launch(void* const* d_in, const int* in_sizes, int n_in,
                              void* d_out, int out_size, void* d_ws, size_t ws_size,
                              hipStream_t stream) {
    const float* h = (const float*)d_in[0];
    // d_in[1] (memory) is dead: k == MEMORY_SIZE, every row is overwritten.
    float* out = (float*)d_out;
    uint32_t* imp_u = (uint32_t*)d_ws;

    importance_kernel<<<S_TOK / 4, 256, 0, stream>>>((const float4*)h, imp_u);
    rank_gather_kernel<<<K_TOP, 256, 0, stream>>>(imp_u, (const float4*)h, (float4*)out);
}